// Round 8
// baseline (869.350 us; speedup 1.0000x reference)
//
#include <hip/hip_runtime.h>
#include <math.h>

// DualRec 2-layer transformer-XL model, MI355X — round 8.
// KEY FIX vs r7: MFMA operand swap — compute (A·B)^T so each lane owns 4
// consecutive C columns; epilogue stores 8B-packed bf16 / float4 fp32 instead
// of 64 scattered 2B stores (r7 counters showed 2x HBM write amplification:
// WRITE_SIZE 69.6MB for a 33.5MB C). Same swap in attention PV (P pre-scaled
// by 1/l before LDS). add_ln: wave-per-row, uint4, no barriers. embed/writeout
// vectorized 8/thread. External tensors bf16 OR fp32 (probe ln_attn_w[0]).
// Workspace 95 MB.

#define S_  512
#define B_  32
#define D_  512
#define NH  8
#define DH  64
#define DI  2048
#define M_  (S_*B_)
#define QKV_LD 1536
#define WL  3407872   // per-layer wbuf elements (6.5 MiB)
#define FP32_ONE 0x3F800000u

typedef unsigned short ushort_t;
typedef __attribute__((ext_vector_type(8))) short short8;
typedef __attribute__((ext_vector_type(4))) float f32x4;

__constant__ int OMEGA_C[8] = {2, 3, 4, 5, 7, 11, 21, 50};

__device__ __forceinline__ float b2f(ushort_t us) {
    return __uint_as_float(((unsigned int)us) << 16);
}
__device__ __forceinline__ ushort_t f2b(float f) {
    unsigned int u = __float_as_uint(f);
    return (ushort_t)((u + 0x7fffu + ((u >> 16) & 1u)) >> 16);
}
__device__ __forceinline__ float ldx(const void* p, size_t idx, bool isbf) {
    return isbf ? b2f(((const ushort_t*)p)[idx]) : ((const float*)p)[idx];
}
__device__ __forceinline__ void async16(const ushort_t* g, ushort_t* l) {
    __builtin_amdgcn_global_load_lds(
        (const __attribute__((address_space(1))) unsigned int*)g,
        (__attribute__((address_space(3))) unsigned int*)l, 16, 0, 0);
}

// ---- DPP reductions ----
#define DPPA(v, ctrl) v += __int_as_float(__builtin_amdgcn_update_dpp(0, __float_as_int(v), ctrl, 0xf, 0xf, true))
__device__ __forceinline__ void dpp_sum64(float& v) {
    DPPA(v, 0x111); DPPA(v, 0x112); DPPA(v, 0x114);
    DPPA(v, 0x118); DPPA(v, 0x142); DPPA(v, 0x143);
}
#define DPPROR(v, ctrl) __int_as_float(__builtin_amdgcn_update_dpp(__float_as_int(v), __float_as_int(v), ctrl, 0xf, 0xf, false))
__device__ __forceinline__ float row16_sum(float v) {
    v += DPPROR(v, 0x128); v += DPPROR(v, 0x124);
    v += DPPROR(v, 0x122); v += DPPROR(v, 0x121);
    return v;
}
__device__ __forceinline__ float row16_max(float v) {
    v = fmaxf(v, DPPROR(v, 0x128)); v = fmaxf(v, DPPROR(v, 0x124));
    v = fmaxf(v, DPPROR(v, 0x122)); v = fmaxf(v, DPPROR(v, 0x121));
    return v;
}
__device__ __forceinline__ float rlane(float v, int l) {
    return __int_as_float(__builtin_amdgcn_readlane(__float_as_int(v), l));
}

// 8 elems/thread gather-embed
__global__ __launch_bounds__(256) void embed_kernel(const int* __restrict__ ids,
                                                    const void* __restrict__ emb,
                                                    ushort_t* __restrict__ h,
                                                    const unsigned int* __restrict__ dtp) {
    const bool isbf = (dtp[0] != FP32_ONE);
    int idx = blockIdx.x * 256 + threadIdx.x;        // over M_*D_/8
    int d8 = idx & 63;
    int row = idx >> 6;                              // i*B + b
    int s = row >> 5, b = row & 31;
    int id = ids[b * S_ + s];
    size_t src = (size_t)id * D_ + d8 * 8;
    if (isbf) {
        *(uint4*)(h + (size_t)row * D_ + d8 * 8) = *(const uint4*)((const ushort_t*)emb + src);
    } else {
        const float* e = (const float*)emb + src;
        float4 a0 = ((const float4*)e)[0], a1 = ((const float4*)e)[1];
        uint4 pk;
        pk.x = (unsigned)f2b(a0.x) | ((unsigned)f2b(a0.y) << 16);
        pk.y = (unsigned)f2b(a0.z) | ((unsigned)f2b(a0.w) << 16);
        pk.z = (unsigned)f2b(a1.x) | ((unsigned)f2b(a1.y) << 16);
        pk.w = (unsigned)f2b(a1.z) | ((unsigned)f2b(a1.w) << 16);
        *(uint4*)(h + (size_t)row * D_ + d8 * 8) = pk;
    }
}

__global__ __launch_bounds__(256) void posemb_kernel(ushort_t* __restrict__ pos) {
    int flat = blockIdx.x * 256 + threadIdx.x;       // over 1024*256
    int p = flat >> 8, k = flat & 255;
    float inv = expf((float)k * -0.035977892078031f);
    float val = (512.0f - (float)p) * inv;
    pos[p * D_ + k]       = f2b(sinf(val));
    pos[p * D_ + 256 + k] = f2b(cosf(val));
}

__global__ __launch_bounds__(256) void transp_cvt4(
    const void* __restrict__ s0, const void* __restrict__ s1,
    const void* __restrict__ s2, const void* __restrict__ s3,
    ushort_t* __restrict__ wbuf, const unsigned int* __restrict__ dtp) {
    const bool isbf = (dtp[0] != FP32_ONE);
    __shared__ float tt[32][33];
    int z = blockIdx.z, layer = z >> 2, t4 = z & 3;
    const void* srcs[4] = {s0, s1, s2, s3};
    const void* in = srcs[t4];
    size_t inoff = (size_t)layer * 262144;
    ushort_t* out = wbuf + (size_t)layer * WL + (size_t)t4 * 262144;
    int tx = threadIdx.x & 31, ty = threadIdx.x >> 5;
    int n0 = blockIdx.x * 32, k0 = blockIdx.y * 32;
#pragma unroll
    for (int it = 0; it < 4; ++it)
        tt[ty + it * 8][tx] = ldx(in, inoff + (size_t)(k0 + ty + it * 8) * 512 + n0 + tx, isbf);
    __syncthreads();
#pragma unroll
    for (int it = 0; it < 4; ++it)
        out[(size_t)(n0 + ty + it * 8) * 512 + k0 + tx] = f2b(tt[tx][ty + it * 8]);
}

__global__ __launch_bounds__(256) void transp_cvtL(const void* __restrict__ in, size_t perlin,
                                                   ushort_t* __restrict__ wbuf, size_t outoff,
                                                   const unsigned int* __restrict__ dtp,
                                                   int K, int N) {
    const bool isbf = (dtp[0] != FP32_ONE);
    __shared__ float tt[32][33];
    int layer = blockIdx.z;
    size_t inoff = (size_t)layer * perlin;
    ushort_t* out = wbuf + (size_t)layer * WL + outoff;
    int tx = threadIdx.x & 31, ty = threadIdx.x >> 5;
    int n0 = blockIdx.x * 32, k0 = blockIdx.y * 32;
#pragma unroll
    for (int it = 0; it < 4; ++it)
        tt[ty + it * 8][tx] = ldx(in, inoff + (size_t)(k0 + ty + it * 8) * N + n0 + tx, isbf);
    __syncthreads();
#pragma unroll
    for (int it = 0; it < 4; ++it)
        out[(size_t)(n0 + ty + it * 8) * K + k0 + tx] = f2b(tt[tx][ty + it * 8]);
}

__global__ __launch_bounds__(256) void cvtL(const void* __restrict__ in, size_t perlin,
                                            ushort_t* __restrict__ wbuf, size_t outoff,
                                            const unsigned int* __restrict__ dtp, int nelem) {
    const bool isbf = (dtp[0] != FP32_ONE);
    int layer = blockIdx.z;
    int i = blockIdx.x * 256 + threadIdx.x;
    if (i < nelem)
        wbuf[(size_t)layer * WL + outoff + i] = f2b(ldx(in, (size_t)layer * perlin + i, isbf));
}

// C[M,N] = A[M,K](bf16, lda) x B^T[n][k](bf16, ldb).
// EPI: 0 none, 1 +bias, 2 +bias+exact GELU.
// OUT: 0 bf16 store, 1 fp32 store, 2 fp32 accumulate (+=).
// Operand-swapped MFMA: D' = (A.B)^T so lane holds row l16 x 4 consecutive
// cols (quad*4+r) -> packed 8B/16B stores, full-line HBM write merging.
template<int EPI, int OUT>
__global__ __launch_bounds__(256)
void mfma_gemm(const ushort_t* __restrict__ A, int lda,
               const ushort_t* __restrict__ Bt, int ldb,
               const void* __restrict__ biasv, size_t biasoff,
               void* __restrict__ Cv, int ldc,
               const unsigned int* __restrict__ dtp, int M, int N, int K) {
    const bool isbf = (dtp[0] != FP32_ONE);
    __shared__ ushort_t As[128 * 32];
    __shared__ ushort_t Bs[128 * 32];
    const int tid = threadIdx.x;
    const int bm = blockIdx.x * 128, bn = blockIdx.y * 128;
    const int w = tid >> 6, lane = tid & 63;
    const int wr = w >> 1, wc = w & 1;
    const int quad = lane >> 4, l16 = lane & 15;
    const int rsub = lane >> 2;
    const int kcg  = (lane & 3) ^ ((rsub >> 1) & 3);
    const int fsw  = (l16 >> 1) & 3;

    f32x4 acc[4][4];
#pragma unroll
    for (int i = 0; i < 4; ++i)
#pragma unroll
        for (int j = 0; j < 4; ++j)
#pragma unroll
            for (int r = 0; r < 4; ++r) acc[i][j][r] = 0.f;

    for (int k0 = 0; k0 < K; k0 += 32) {
#pragma unroll
        for (int c = 0; c < 2; ++c) {
            int grp = c * 4 + w;
            int row = grp * 16 + rsub;
            async16(A  + (size_t)(bm + row) * lda + k0 + kcg * 8, As + grp * 512);
            async16(Bt + (size_t)(bn + row) * ldb + k0 + kcg * 8, Bs + grp * 512);
        }
        __syncthreads();

        short8 af[4], bf[4];
#pragma unroll
        for (int t = 0; t < 4; ++t) {
            int ra = wr * 64 + t * 16 + l16;
            int rb = wc * 64 + t * 16 + l16;
            af[t] = *(const short8*)(As + ra * 32 + ((quad ^ fsw) * 8));
            bf[t] = *(const short8*)(Bs + rb * 32 + ((quad ^ fsw) * 8));
        }
        // swapped: acc[tr][tc] = (A_tile . B_tile)^T fragment
#pragma unroll
        for (int tr = 0; tr < 4; ++tr)
#pragma unroll
            for (int tc = 0; tc < 4; ++tc)
                acc[tr][tc] = __builtin_amdgcn_mfma_f32_16x16x32_bf16(bf[tc], af[tr], acc[tr][tc], 0, 0, 0);
        __syncthreads();
    }

    // epilogue: lane has C[row = tr*16+l16][cols tc*16+quad*4 .. +3]
    float bv[4][4];
    if (EPI >= 1) {
#pragma unroll
        for (int tc = 0; tc < 4; ++tc)
#pragma unroll
            for (int r = 0; r < 4; ++r)
                bv[tc][r] = ldx(biasv, biasoff + bn + wc * 64 + tc * 16 + quad * 4 + r, isbf);
    }
#pragma unroll
    for (int tr = 0; tr < 4; ++tr) {
        int grow = bm + wr * 64 + tr * 16 + l16;
#pragma unroll
        for (int tc = 0; tc < 4; ++tc) {
            int gcb = bn + wc * 64 + tc * 16 + quad * 4;
            float x[4];
#pragma unroll
            for (int r = 0; r < 4; ++r) {
                float v = acc[tr][tc][r];
                if (EPI >= 1) v += bv[tc][r];
                if (EPI == 2) v = 0.5f * v * (1.f + erff(v * 0.7071067811865475f));
                x[r] = v;
            }
            size_t coff = (size_t)grow * ldc + gcb;
            if (OUT == 0) {
                uint2 pk;
                pk.x = (unsigned)f2b(x[0]) | ((unsigned)f2b(x[1]) << 16);
                pk.y = (unsigned)f2b(x[2]) | ((unsigned)f2b(x[3]) << 16);
                *(uint2*)((ushort_t*)Cv + coff) = pk;
            } else if (OUT == 1) {
                *(float4*)((float*)Cv + coff) = make_float4(x[0], x[1], x[2], x[3]);
            } else {
                float4* p = (float4*)((float*)Cv + coff);
                float4 o = *p;
                o.x += x[0]; o.y += x[1]; o.z += x[2]; o.w += x[3];
                *p = o;
            }
        }
    }
}

// MFMA banded attention (r7 structure) with swapped-operand PV epilogue.
__global__ __launch_bounds__(256) void attn_mfma(
    ushort_t* __restrict__ qkv, const ushort_t* __restrict__ krb,
    const void* __restrict__ rwb, const void* __restrict__ rrb, size_t boff,
    const void* __restrict__ im,
    const unsigned int* __restrict__ dtp) {
    const bool isbf = (dtp[0] != FP32_ONE);
    __shared__ ushort_t Ks[128 * 64];
    __shared__ ushort_t VT[64 * 128];
    __shared__ ushort_t Rs[64 * 64];
    __shared__ float    BD2[4 * 16 * 64];
    __shared__ ushort_t Ps[4 * 16 * 128];
    __shared__ float    imk[128];
    __shared__ float    imq[64];

    const int tid = threadIdx.x;
    const int i0 = blockIdx.x * 64;
    const int b  = blockIdx.y;
    const int n  = blockIdx.z;
    const int o  = OMEGA_C[n];
    const int noff = n * DH;
    const int j0 = i0 - 64;
    const int w = tid >> 6, lane = tid & 63;
    const int quad = lane >> 4, l16 = lane & 15;

#pragma unroll
    for (int it = 0; it < 4; ++it) {
        int q4 = it * 256 + tid;
        int c  = q4 >> 3, ch = q4 & 7;
        int jc = j0 + c; jc = jc < 0 ? 0 : jc;
        size_t rowb = (size_t)(jc * B_ + b) * QKV_LD + noff;
        *(uint4*)(Ks + c * 64 + ch * 8) = *(const uint4*)(qkv + rowb + 512 + ch * 8);
        ushort_t v8[8];
        *(uint4*)v8 = *(const uint4*)(qkv + rowb + 1024 + ch * 8);
#pragma unroll
        for (int e = 0; e < 8; ++e) VT[(ch * 8 + e) * 128 + c] = v8[e];
    }
#pragma unroll
    for (int it = 0; it < 2; ++it) {
        int q4 = it * 256 + tid;
        int m = q4 >> 3, ch = q4 & 7;
        *(uint4*)(Rs + m * 64 + ch * 8) =
            *(const uint4*)(krb + (size_t)(512 - m) * 512 + noff + ch * 8);
    }
    if (tid < 128) {
        int j = j0 + tid;
        imk[tid] = (j >= 0) ? ldx(im, b * S_ + j, isbf) : 0.f;
    } else if (tid < 192) {
        imq[tid - 128] = ldx(im, b * S_ + i0 + (tid - 128), isbf);
    }
    __syncthreads();

    const int qrow = i0 + w * 16 + l16;
    size_t qbase = (size_t)(qrow * B_ + b) * QKV_LD + noff;
    short8 aw[2], ar[2];
#pragma unroll
    for (int kc = 0; kc < 2; ++kc) {
        int kof = kc * 32 + quad * 8;
        ushort_t qe[8];
        *(uint4*)qe = *(const uint4*)(qkv + qbase + kof);
#pragma unroll
        for (int e = 0; e < 8; ++e) {
            float f = b2f(qe[e]);
            ((ushort_t*)&aw[kc])[e] = f2b(f + ldx(rwb, boff + noff + kof + e, isbf));
            ((ushort_t*)&ar[kc])[e] = f2b(f + ldx(rrb, boff + noff + kof + e, isbf));
        }
    }

    f32x4 accs[8];
#pragma unroll
    for (int ct = 0; ct < 8; ++ct) {
        short8 b0 = *(const short8*)(Ks + (ct * 16 + l16) * 64 + quad * 8);
        short8 b1 = *(const short8*)(Ks + (ct * 16 + l16) * 64 + 32 + quad * 8);
        f32x4 z = {0.f, 0.f, 0.f, 0.f};
        z = __builtin_amdgcn_mfma_f32_16x16x32_bf16(aw[0], b0, z, 0, 0, 0);
        z = __builtin_amdgcn_mfma_f32_16x16x32_bf16(aw[1], b1, z, 0, 0, 0);
        accs[ct] = z;
    }
    float* BD2w = BD2 + w * 16 * 64;
#pragma unroll
    for (int mt = 0; mt < 4; ++mt) {
        short8 b0 = *(const short8*)(Rs + (mt * 16 + l16) * 64 + quad * 8);
        short8 b1 = *(const short8*)(Rs + (mt * 16 + l16) * 64 + 32 + quad * 8);
        f32x4 z = {0.f, 0.f, 0.f, 0.f};
        z = __builtin_amdgcn_mfma_f32_16x16x32_bf16(ar[0], b0, z, 0, 0, 0);
        z = __builtin_amdgcn_mfma_f32_16x16x32_bf16(ar[1], b1, z, 0, 0, 0);
#pragma unroll
        for (int r = 0; r < 4; ++r)
            BD2w[(quad * 4 + r) * 64 + mt * 16 + l16] = z[r];
    }

    float im_i[4];
#pragma unroll
    for (int r = 0; r < 4; ++r) im_i[r] = imq[w * 16 + quad * 4 + r];

    float sc[8][4];
#pragma unroll
    for (int ct = 0; ct < 8; ++ct) {
        int cl = ct * 16 + l16;
        float imk_c = imk[cl];
#pragma unroll
        for (int r = 0; r < 4; ++r) {
            int qrl = w * 16 + quad * 4 + r;
            int rel = qrl + 64 - cl;
            int relc = rel < 0 ? 0 : (rel > 63 ? 63 : rel);
            float bd = BD2w[(quad * 4 + r) * 64 + relc];
            bool valid = (rel >= 0) && (rel < o) && (rel <= i0 + qrl)
                         && (im_i[r] + imk_c <= 0.f);
            sc[ct][r] = valid ? (accs[ct][r] + bd) * 0.125f : -1e30f;
        }
    }
    float rl[4];
#pragma unroll
    for (int r = 0; r < 4; ++r) {
        float mx = sc[0][r];
#pragma unroll
        for (int ct = 1; ct < 8; ++ct) mx = fmaxf(mx, sc[ct][r]);
        mx = row16_max(mx);
        float l = 0.f;
#pragma unroll
        for (int ct = 0; ct < 8; ++ct) {
            float pv = expf(sc[ct][r] - mx);
            sc[ct][r] = pv;
            l += pv;
        }
        l = row16_sum(l);
        rl[r] = 1.f / l;
    }
    // P (pre-scaled by 1/l) to LDS, then swapped-operand PV
    ushort_t* Pw = Ps + w * 16 * 128;
#pragma unroll
    for (int ct = 0; ct < 8; ++ct)
#pragma unroll
        for (int r = 0; r < 4; ++r)
            Pw[(quad * 4 + r) * 128 + ct * 16 + l16] = f2b(sc[ct][r] * rl[r]);

    short8 aP[4];
#pragma unroll
    for (int kc = 0; kc < 4; ++kc)
        aP[kc] = *(const short8*)(Pw + l16 * 128 + kc * 32 + quad * 8);

    const int qg = i0 + w * 16 + l16;
    const size_t obase = (size_t)(qg * B_ + b) * QKV_LD + noff;
#pragma unroll
    for (int dt = 0; dt < 4; ++dt) {
        f32x4 accO = {0.f, 0.f, 0.f, 0.f};
#pragma unroll
        for (int kc = 0; kc < 4; ++kc) {
            short8 bV = *(const short8*)(VT + (dt * 16 + l16) * 128 + kc * 32 + quad * 8);
            accO = __builtin_amdgcn_mfma_f32_16x16x32_bf16(aP[kc], bV, accO, 0, 0, 0);
        }
        // swapped PV would need V^T as A-operand fragment per output row; we
        // instead swap at the tile level: compute O^T = mfma(bV_asA, aP_asB).
        // bV here was read as B-operand rows (d=dt*16+l16): as A-operand it is
        // exactly V^T[m=d][k]; aP as B-operand is P^T[k][n=q]. Do the swap:
        f32x4 accT = {0.f, 0.f, 0.f, 0.f};
#pragma unroll
        for (int kc = 0; kc < 4; ++kc) {
            short8 bV = *(const short8*)(VT + (dt * 16 + l16) * 128 + kc * 32 + quad * 8);
            accT = __builtin_amdgcn_mfma_f32_16x16x32_bf16(bV, aP[kc], accT, 0, 0, 0);
        }
        (void)accO;
        // accT[r]: O[q = l16][d = dt*16 + quad*4 + r] -> 8B packed store
        uint2 pk;
        pk.x = (unsigned)f2b(accT[0]) | ((unsigned)f2b(accT[1]) << 16);
        pk.y = (unsigned)f2b(accT[2]) | ((unsigned)f2b(accT[3]) << 16);
        *(uint2*)(qkv + obase + dt * 16 + quad * 4) = pk;
    }
}

// h = LayerNorm(x + h)*w + b. Wave-per-row (4 rows/block), uint4, no barriers.
template<int XF>
__global__ __launch_bounds__(256) void add_ln_kernel(
    const void* __restrict__ x, ushort_t* __restrict__ h,
    const void* __restrict__ w, const void* __restrict__ b, size_t boff,
    const unsigned int* __restrict__ dtp) {
    const bool isbf = (dtp[0] != FP32_ONE);
    int lane = threadIdx.x & 63;
    int row = blockIdx.x * 4 + (threadIdx.x >> 6);
    size_t base = (size_t)row * D_ + lane * 8;
    float v[8];
    if (XF) {
        const float* xp = (const float*)x + base;
        float4 a0 = ((const float4*)xp)[0], a1 = ((const float4*)xp)[1];
        v[0] = a0.x; v[1] = a0.y; v[2] = a0.z; v[3] = a0.w;
        v[4] = a1.x; v[5] = a1.y; v[6] = a1.z; v[7] = a1.w;
    } else {
        ushort_t xe[8];
        *(uint4*)xe = *(const uint4*)((const ushort_t*)x + base);
#pragma unroll
        for (int e = 0; e < 8; ++e) v[e] = b2f(xe[e]);
    }
    ushort_t he[8];
    *(uint4*)he = *(const uint4*)(h + base);
    float s = 0.f, ss = 0.f;
#pragma unroll
    for (int e = 0; e < 8; ++e) {
        v[e] += b2f(he[e]);
        s += v[e]; ss += v[e] * v[e];
    }
    dpp_sum64(s); dpp_sum64(ss);
    float S = rlane(s, 63), SS = rlane(ss, 63);
    float mu  = S * (1.f / D_);
    float var = fmaxf(SS * (1.f / D_) - mu * mu, 0.f);
    float inv = rsqrtf(var + 1e-8f);
    ushort_t oe[8];
#pragma unroll
    for (int e = 0; e < 8; ++e)
        oe[e] = f2b((v[e] - mu) * inv * ldx(w, boff + lane * 8 + e, isbf)
                    + ldx(b, boff + lane * 8 + e, isbf));
    *(uint4*)(h + base) = *(uint4*)oe;
}

// out[b][s][:] = h[(s*B+b)][:], 8 elems/thread
__global__ __launch_bounds__(256) void writeout_kernel(const ushort_t* __restrict__ h,
                                                       void* __restrict__ out,
                                                       const unsigned int* __restrict__ dtp) {
    const bool isbf = (dtp[0] != FP32_ONE);
    int idx = blockIdx.x * 256 + threadIdx.x;        // over M_*D_/8
    int d8 = idx & 63;
    int rest = idx >> 6;                             // b*S + s
    int s = rest & (S_ - 1), b = rest >> 9;
    ushort_t ve[8];
    *(uint4*)ve = *(const uint4*)(h + ((size_t)(s * B_ + b) << 9) + d8 * 8);
    if (isbf) {
        *(uint4*)((ushort_t*)out + (size_t)idx * 8) = *(uint4*)ve;
    } else {
        float* op = (float*)out + (size_t)idx * 8;
        ((float4*)op)[0] = make_float4(b2f(ve[0]), b2f(ve[1]), b2f(ve[2]), b2f(ve[3]));
        ((float4*)op)[1] = make_float4(b2f(ve[4]), b2f(ve[5]), b2f(ve[6]), b2f(ve[7]));
    }
}

extern "C" void kernel_launch(void* const* d_in, const int* in_sizes, int n_in,
                              void* d_out, int out_size, void* d_ws, size_t ws_size,
                              hipStream_t stream) {
    (void)in_sizes; (void)n_in; (void)out_size; (void)ws_size;
    const int*  ids = (const int*)d_in[0];
    const void* im  = d_in[1];
    const void* emb = d_in[2];
    const void* Wq = d_in[3], *Wk = d_in[4], *Wv = d_in[5], *Wr = d_in[6], *Wo = d_in[7];
    const void* rrb = d_in[8], *rwb = d_in[9];
    const void* lnaw = d_in[10], *lnab = d_in[11];
    const void* W1 = d_in[12], *b1 = d_in[13], *W2 = d_in[14], *b2 = d_in[15];
    const void* lnfw = d_in[16], *lnfb = d_in[17];
    const unsigned int* dtp = (const unsigned int*)d_in[10];  // dtype probe

    // ---- workspace layout, 95 MB ----
    char* wsb = (char*)d_ws;
    ushort_t* h     = (ushort_t*)wsb;                  // [0,16) bf16 16384x512
    ushort_t* qkv   = (ushort_t*)(wsb + (16u << 20));  // [16,64) bf16 16384x1536
    ushort_t* ff1c  = (ushort_t*)(wsb + (16u << 20));  // FF: [16,48) bf16 16384x1024
    float*    acc32 = (float*)   (wsb + (48u << 20));  // FF: [48,80) fp32 16384x512
    ushort_t* tmp   = (ushort_t*)(wsb + (64u << 20));  // [64,80) bf16 16384x512
    ushort_t* wbuf  = (ushort_t*)(wsb + (80u << 20));  // [80,93) weights
    ushort_t* posb  = (ushort_t*)(wsb + (93u << 20));  // [93,94)
    ushort_t* krb   = (ushort_t*)(wsb + (94u << 20));  // [94,95)

    embed_kernel<<<4096, 256, 0, stream>>>(ids, emb, h, dtp);
    posemb_kernel<<<1024, 256, 0, stream>>>(posb);

    transp_cvt4<<<dim3(16, 16, 8), 256, 0, stream>>>(Wq, Wk, Wv, Wr, wbuf, dtp);
    cvtL<<<dim3(1024, 1, 2), 256, 0, stream>>>(Wo, 262144, wbuf, 1048576, dtp, 262144);
    transp_cvtL<<<dim3(64, 16, 2), 256, 0, stream>>>(W1, 1048576, wbuf, 1310720, dtp, 512, 2048);
    transp_cvtL<<<dim3(16, 64, 2), 256, 0, stream>>>(W2, 1048576, wbuf, 2359296, dtp, 2048, 512);

    for (int l = 0; l < 2; ++l) {
        size_t boff = (size_t)l * 512;
        size_t b1off = (size_t)l * 2048;
        ushort_t* qkvT = wbuf + (size_t)l * WL;
        ushort_t* wrT  = qkvT + 786432;
        ushort_t* woc  = wrT  + 262144;
        ushort_t* w1T  = woc  + 262144;
        ushort_t* w2T  = w1T  + 1048576;

        mfma_gemm<0,0><<<dim3(8, 4), 256, 0, stream>>>(posb, 512, wrT, 512, nullptr, 0, krb, 512, dtp, 1024, 512, 512);
        mfma_gemm<0,0><<<dim3(128, 12), 256, 0, stream>>>(h, 512, qkvT, 512, nullptr, 0, qkv, QKV_LD, dtp, M_, QKV_LD, 512);

        attn_mfma<<<dim3(8, 32, 8), 256, 0, stream>>>(qkv, krb, rwb, rrb, boff, im, dtp);

        mfma_gemm<0,0><<<dim3(128, 4), 256, 0, stream>>>(qkv, QKV_LD, woc, 512, nullptr, 0, tmp, 512, dtp, M_, 512, 512);
        add_ln_kernel<0><<<4096, 256, 0, stream>>>(tmp, h, lnaw, lnab, boff, dtp);

        for (int nh = 0; nh < 2; ++nh) {
            ushort_t* w1part = w1T + (size_t)nh * 1024 * 512;
            ushort_t* w2part = w2T + (size_t)nh * 1024;
            mfma_gemm<2,0><<<dim3(128, 8), 256, 0, stream>>>(h, 512, w1part, 512, b1, b1off + nh * 1024, ff1c, 1024, dtp, M_, 1024, 512);
            if (nh == 0)
                mfma_gemm<1,1><<<dim3(128, 4), 256, 0, stream>>>(ff1c, 1024, w2part, 2048, b2, boff, acc32, 512, dtp, M_, 512, 1024);
            else
                mfma_gemm<0,2><<<dim3(128, 4), 256, 0, stream>>>(ff1c, 1024, w2part, 2048, nullptr, 0, acc32, 512, dtp, M_, 512, 1024);
        }
        add_ln_kernel<1><<<4096, 256, 0, stream>>>(acc32, h, lnfw, lnfb, boff, dtp);
    }

    writeout_kernel<<<4096, 256, 0, stream>>>(h, d_out, dtp);
}

// Round 9
// 811.591 us; speedup vs baseline: 1.0712x; 1.0712x over previous
//
#include <hip/hip_runtime.h>
#include <math.h>

// DualRec 2-layer transformer-XL model, MI355X — round 9.
// r8 counters revealed ws_size ≈ 400 MB (poison fill WRITE_SIZE) — drop all
// buffer aliasing contortions: FFN un-split (FF1 single N=2048 launch, FF2
// single K=2048 GEMM, bf16 out; acc32 fp32-RMW pass eliminated −134 MB).
// Attention: removed r8's dead un-swapped PV loop. k_r GEMMs hoisted.
// GEMM: swapped-operand 128x128x32 bf16 MFMA (packed 8B C-stores),
// global_load_lds staging, XOR-swizzled LDS. Workspace 160 MB.

#define S_  512
#define B_  32
#define D_  512
#define NH  8
#define DH  64
#define DI  2048
#define M_  (S_*B_)
#define QKV_LD 1536
#define WL  3407872   // per-layer wbuf elements (6.5 MiB)
#define FP32_ONE 0x3F800000u

typedef unsigned short ushort_t;
typedef __attribute__((ext_vector_type(8))) short short8;
typedef __attribute__((ext_vector_type(4))) float f32x4;

__constant__ int OMEGA_C[8] = {2, 3, 4, 5, 7, 11, 21, 50};

__device__ __forceinline__ float b2f(ushort_t us) {
    return __uint_as_float(((unsigned int)us) << 16);
}
__device__ __forceinline__ ushort_t f2b(float f) {
    unsigned int u = __float_as_uint(f);
    return (ushort_t)((u + 0x7fffu + ((u >> 16) & 1u)) >> 16);
}
__device__ __forceinline__ float ldx(const void* p, size_t idx, bool isbf) {
    return isbf ? b2f(((const ushort_t*)p)[idx]) : ((const float*)p)[idx];
}
__device__ __forceinline__ void async16(const ushort_t* g, ushort_t* l) {
    __builtin_amdgcn_global_load_lds(
        (const __attribute__((address_space(1))) unsigned int*)g,
        (__attribute__((address_space(3))) unsigned int*)l, 16, 0, 0);
}

// ---- DPP reductions ----
#define DPPA(v, ctrl) v += __int_as_float(__builtin_amdgcn_update_dpp(0, __float_as_int(v), ctrl, 0xf, 0xf, true))
__device__ __forceinline__ void dpp_sum64(float& v) {
    DPPA(v, 0x111); DPPA(v, 0x112); DPPA(v, 0x114);
    DPPA(v, 0x118); DPPA(v, 0x142); DPPA(v, 0x143);
}
#define DPPROR(v, ctrl) __int_as_float(__builtin_amdgcn_update_dpp(__float_as_int(v), __float_as_int(v), ctrl, 0xf, 0xf, false))
__device__ __forceinline__ float row16_sum(float v) {
    v += DPPROR(v, 0x128); v += DPPROR(v, 0x124);
    v += DPPROR(v, 0x122); v += DPPROR(v, 0x121);
    return v;
}
__device__ __forceinline__ float row16_max(float v) {
    v = fmaxf(v, DPPROR(v, 0x128)); v = fmaxf(v, DPPROR(v, 0x124));
    v = fmaxf(v, DPPROR(v, 0x122)); v = fmaxf(v, DPPROR(v, 0x121));
    return v;
}
__device__ __forceinline__ float rlane(float v, int l) {
    return __int_as_float(__builtin_amdgcn_readlane(__float_as_int(v), l));
}

__global__ __launch_bounds__(256) void embed_kernel(const int* __restrict__ ids,
                                                    const void* __restrict__ emb,
                                                    ushort_t* __restrict__ h,
                                                    const unsigned int* __restrict__ dtp) {
    const bool isbf = (dtp[0] != FP32_ONE);
    int idx = blockIdx.x * 256 + threadIdx.x;        // over M_*D_/8
    int d8 = idx & 63;
    int row = idx >> 6;                              // i*B + b
    int s = row >> 5, b = row & 31;
    int id = ids[b * S_ + s];
    size_t src = (size_t)id * D_ + d8 * 8;
    if (isbf) {
        *(uint4*)(h + (size_t)row * D_ + d8 * 8) = *(const uint4*)((const ushort_t*)emb + src);
    } else {
        const float* e = (const float*)emb + src;
        float4 a0 = ((const float4*)e)[0], a1 = ((const float4*)e)[1];
        uint4 pk;
        pk.x = (unsigned)f2b(a0.x) | ((unsigned)f2b(a0.y) << 16);
        pk.y = (unsigned)f2b(a0.z) | ((unsigned)f2b(a0.w) << 16);
        pk.z = (unsigned)f2b(a1.x) | ((unsigned)f2b(a1.y) << 16);
        pk.w = (unsigned)f2b(a1.z) | ((unsigned)f2b(a1.w) << 16);
        *(uint4*)(h + (size_t)row * D_ + d8 * 8) = pk;
    }
}

__global__ __launch_bounds__(256) void posemb_kernel(ushort_t* __restrict__ pos) {
    int flat = blockIdx.x * 256 + threadIdx.x;       // over 1024*256
    int p = flat >> 8, k = flat & 255;
    float inv = expf((float)k * -0.035977892078031f);
    float val = (512.0f - (float)p) * inv;
    pos[p * D_ + k]       = f2b(sinf(val));
    pos[p * D_ + 256 + k] = f2b(cosf(val));
}

__global__ __launch_bounds__(256) void transp_cvt4(
    const void* __restrict__ s0, const void* __restrict__ s1,
    const void* __restrict__ s2, const void* __restrict__ s3,
    ushort_t* __restrict__ wbuf, const unsigned int* __restrict__ dtp) {
    const bool isbf = (dtp[0] != FP32_ONE);
    __shared__ float tt[32][33];
    int z = blockIdx.z, layer = z >> 2, t4 = z & 3;
    const void* srcs[4] = {s0, s1, s2, s3};
    const void* in = srcs[t4];
    size_t inoff = (size_t)layer * 262144;
    ushort_t* out = wbuf + (size_t)layer * WL + (size_t)t4 * 262144;
    int tx = threadIdx.x & 31, ty = threadIdx.x >> 5;
    int n0 = blockIdx.x * 32, k0 = blockIdx.y * 32;
#pragma unroll
    for (int it = 0; it < 4; ++it)
        tt[ty + it * 8][tx] = ldx(in, inoff + (size_t)(k0 + ty + it * 8) * 512 + n0 + tx, isbf);
    __syncthreads();
#pragma unroll
    for (int it = 0; it < 4; ++it)
        out[(size_t)(n0 + ty + it * 8) * 512 + k0 + tx] = f2b(tt[tx][ty + it * 8]);
}

__global__ __launch_bounds__(256) void transp_cvtL(const void* __restrict__ in, size_t perlin,
                                                   ushort_t* __restrict__ wbuf, size_t outoff,
                                                   const unsigned int* __restrict__ dtp,
                                                   int K, int N) {
    const bool isbf = (dtp[0] != FP32_ONE);
    __shared__ float tt[32][33];
    int layer = blockIdx.z;
    size_t inoff = (size_t)layer * perlin;
    ushort_t* out = wbuf + (size_t)layer * WL + outoff;
    int tx = threadIdx.x & 31, ty = threadIdx.x >> 5;
    int n0 = blockIdx.x * 32, k0 = blockIdx.y * 32;
#pragma unroll
    for (int it = 0; it < 4; ++it)
        tt[ty + it * 8][tx] = ldx(in, inoff + (size_t)(k0 + ty + it * 8) * N + n0 + tx, isbf);
    __syncthreads();
#pragma unroll
    for (int it = 0; it < 4; ++it)
        out[(size_t)(n0 + ty + it * 8) * K + k0 + tx] = f2b(tt[tx][ty + it * 8]);
}

__global__ __launch_bounds__(256) void cvtL(const void* __restrict__ in, size_t perlin,
                                            ushort_t* __restrict__ wbuf, size_t outoff,
                                            const unsigned int* __restrict__ dtp, int nelem) {
    const bool isbf = (dtp[0] != FP32_ONE);
    int layer = blockIdx.z;
    int i = blockIdx.x * 256 + threadIdx.x;
    if (i < nelem)
        wbuf[(size_t)layer * WL + outoff + i] = f2b(ldx(in, (size_t)layer * perlin + i, isbf));
}

// C[M,N] = A[M,K](bf16, lda) x B^T[n][k](bf16, ldb).
// EPI: 0 none, 1 +bias, 2 +bias+exact GELU. Swapped-operand MFMA: lane owns
// C[row l16][4 consecutive cols] -> 8B packed bf16 stores.
template<int EPI>
__global__ __launch_bounds__(256)
void mfma_gemm(const ushort_t* __restrict__ A, int lda,
               const ushort_t* __restrict__ Bt, int ldb,
               const void* __restrict__ biasv, size_t biasoff,
               ushort_t* __restrict__ C, int ldc,
               const unsigned int* __restrict__ dtp, int M, int N, int K) {
    const bool isbf = (dtp[0] != FP32_ONE);
    __shared__ ushort_t As[128 * 32];
    __shared__ ushort_t Bs[128 * 32];
    const int tid = threadIdx.x;
    const int bm = blockIdx.x * 128, bn = blockIdx.y * 128;
    const int w = tid >> 6, lane = tid & 63;
    const int wr = w >> 1, wc = w & 1;
    const int quad = lane >> 4, l16 = lane & 15;
    const int rsub = lane >> 2;
    const int kcg  = (lane & 3) ^ ((rsub >> 1) & 3);
    const int fsw  = (l16 >> 1) & 3;

    f32x4 acc[4][4];
#pragma unroll
    for (int i = 0; i < 4; ++i)
#pragma unroll
        for (int j = 0; j < 4; ++j)
#pragma unroll
            for (int r = 0; r < 4; ++r) acc[i][j][r] = 0.f;

    for (int k0 = 0; k0 < K; k0 += 32) {
#pragma unroll
        for (int c = 0; c < 2; ++c) {
            int grp = c * 4 + w;
            int row = grp * 16 + rsub;
            async16(A  + (size_t)(bm + row) * lda + k0 + kcg * 8, As + grp * 512);
            async16(Bt + (size_t)(bn + row) * ldb + k0 + kcg * 8, Bs + grp * 512);
        }
        __syncthreads();

        short8 af[4], bf[4];
#pragma unroll
        for (int t = 0; t < 4; ++t) {
            int ra = wr * 64 + t * 16 + l16;
            int rb = wc * 64 + t * 16 + l16;
            af[t] = *(const short8*)(As + ra * 32 + ((quad ^ fsw) * 8));
            bf[t] = *(const short8*)(Bs + rb * 32 + ((quad ^ fsw) * 8));
        }
#pragma unroll
        for (int tr = 0; tr < 4; ++tr)
#pragma unroll
            for (int tc = 0; tc < 4; ++tc)
                acc[tr][tc] = __builtin_amdgcn_mfma_f32_16x16x32_bf16(bf[tc], af[tr], acc[tr][tc], 0, 0, 0);
        __syncthreads();
    }

    float bv[4][4];
    if (EPI >= 1) {
#pragma unroll
        for (int tc = 0; tc < 4; ++tc)
#pragma unroll
            for (int r = 0; r < 4; ++r)
                bv[tc][r] = ldx(biasv, biasoff + bn + wc * 64 + tc * 16 + quad * 4 + r, isbf);
    }
#pragma unroll
    for (int tr = 0; tr < 4; ++tr) {
        int grow = bm + wr * 64 + tr * 16 + l16;
#pragma unroll
        for (int tc = 0; tc < 4; ++tc) {
            int gcb = bn + wc * 64 + tc * 16 + quad * 4;
            float x[4];
#pragma unroll
            for (int r = 0; r < 4; ++r) {
                float v = acc[tr][tc][r];
                if (EPI >= 1) v += bv[tc][r];
                if (EPI == 2) v = 0.5f * v * (1.f + erff(v * 0.7071067811865475f));
                x[r] = v;
            }
            uint2 pk;
            pk.x = (unsigned)f2b(x[0]) | ((unsigned)f2b(x[1]) << 16);
            pk.y = (unsigned)f2b(x[2]) | ((unsigned)f2b(x[3]) << 16);
            *(uint2*)(C + (size_t)grow * ldc + gcb) = pk;
        }
    }
}

// MFMA banded attention; PV uses swapped operands (packed 8B output stores).
__global__ __launch_bounds__(256) void attn_mfma(
    ushort_t* __restrict__ qkv, const ushort_t* __restrict__ krb,
    const void* __restrict__ rwb, const void* __restrict__ rrb, size_t boff,
    const void* __restrict__ im,
    const unsigned int* __restrict__ dtp) {
    const bool isbf = (dtp[0] != FP32_ONE);
    __shared__ ushort_t Ks[128 * 64];
    __shared__ ushort_t VT[64 * 128];
    __shared__ ushort_t Rs[64 * 64];
    __shared__ float    BD2[4 * 16 * 64];
    __shared__ ushort_t Ps[4 * 16 * 128];
    __shared__ float    imk[128];
    __shared__ float    imq[64];

    const int tid = threadIdx.x;
    const int i0 = blockIdx.x * 64;
    const int b  = blockIdx.y;
    const int n  = blockIdx.z;
    const int o  = OMEGA_C[n];
    const int noff = n * DH;
    const int j0 = i0 - 64;
    const int w = tid >> 6, lane = tid & 63;
    const int quad = lane >> 4, l16 = lane & 15;

#pragma unroll
    for (int it = 0; it < 4; ++it) {
        int q4 = it * 256 + tid;
        int c  = q4 >> 3, ch = q4 & 7;
        int jc = j0 + c; jc = jc < 0 ? 0 : jc;
        size_t rowb = (size_t)(jc * B_ + b) * QKV_LD + noff;
        *(uint4*)(Ks + c * 64 + ch * 8) = *(const uint4*)(qkv + rowb + 512 + ch * 8);
        ushort_t v8[8];
        *(uint4*)v8 = *(const uint4*)(qkv + rowb + 1024 + ch * 8);
#pragma unroll
        for (int e = 0; e < 8; ++e) VT[(ch * 8 + e) * 128 + c] = v8[e];
    }
#pragma unroll
    for (int it = 0; it < 2; ++it) {
        int q4 = it * 256 + tid;
        int m = q4 >> 3, ch = q4 & 7;
        *(uint4*)(Rs + m * 64 + ch * 8) =
            *(const uint4*)(krb + (size_t)(512 - m) * 512 + noff + ch * 8);
    }
    if (tid < 128) {
        int j = j0 + tid;
        imk[tid] = (j >= 0) ? ldx(im, b * S_ + j, isbf) : 0.f;
    } else if (tid < 192) {
        imq[tid - 128] = ldx(im, b * S_ + i0 + (tid - 128), isbf);
    }
    __syncthreads();

    const int qrow = i0 + w * 16 + l16;
    size_t qbase = (size_t)(qrow * B_ + b) * QKV_LD + noff;
    short8 aw[2], ar[2];
#pragma unroll
    for (int kc = 0; kc < 2; ++kc) {
        int kof = kc * 32 + quad * 8;
        ushort_t qe[8];
        *(uint4*)qe = *(const uint4*)(qkv + qbase + kof);
#pragma unroll
        for (int e = 0; e < 8; ++e) {
            float f = b2f(qe[e]);
            ((ushort_t*)&aw[kc])[e] = f2b(f + ldx(rwb, boff + noff + kof + e, isbf));
            ((ushort_t*)&ar[kc])[e] = f2b(f + ldx(rrb, boff + noff + kof + e, isbf));
        }
    }

    f32x4 accs[8];
#pragma unroll
    for (int ct = 0; ct < 8; ++ct) {
        short8 b0 = *(const short8*)(Ks + (ct * 16 + l16) * 64 + quad * 8);
        short8 b1 = *(const short8*)(Ks + (ct * 16 + l16) * 64 + 32 + quad * 8);
        f32x4 z = {0.f, 0.f, 0.f, 0.f};
        z = __builtin_amdgcn_mfma_f32_16x16x32_bf16(aw[0], b0, z, 0, 0, 0);
        z = __builtin_amdgcn_mfma_f32_16x16x32_bf16(aw[1], b1, z, 0, 0, 0);
        accs[ct] = z;
    }
    float* BD2w = BD2 + w * 16 * 64;
#pragma unroll
    for (int mt = 0; mt < 4; ++mt) {
        short8 b0 = *(const short8*)(Rs + (mt * 16 + l16) * 64 + quad * 8);
        short8 b1 = *(const short8*)(Rs + (mt * 16 + l16) * 64 + 32 + quad * 8);
        f32x4 z = {0.f, 0.f, 0.f, 0.f};
        z = __builtin_amdgcn_mfma_f32_16x16x32_bf16(ar[0], b0, z, 0, 0, 0);
        z = __builtin_amdgcn_mfma_f32_16x16x32_bf16(ar[1], b1, z, 0, 0, 0);
#pragma unroll
        for (int r = 0; r < 4; ++r)
            BD2w[(quad * 4 + r) * 64 + mt * 16 + l16] = z[r];
    }

    float im_i[4];
#pragma unroll
    for (int r = 0; r < 4; ++r) im_i[r] = imq[w * 16 + quad * 4 + r];

    float sc[8][4];
#pragma unroll
    for (int ct = 0; ct < 8; ++ct) {
        int cl = ct * 16 + l16;
        float imk_c = imk[cl];
#pragma unroll
        for (int r = 0; r < 4; ++r) {
            int qrl = w * 16 + quad * 4 + r;
            int rel = qrl + 64 - cl;
            int relc = rel < 0 ? 0 : (rel > 63 ? 63 : rel);
            float bd = BD2w[(quad * 4 + r) * 64 + relc];
            bool valid = (rel >= 0) && (rel < o) && (rel <= i0 + qrl)
                         && (im_i[r] + imk_c <= 0.f);
            sc[ct][r] = valid ? (accs[ct][r] + bd) * 0.125f : -1e30f;
        }
    }
    float rl[4];
#pragma unroll
    for (int r = 0; r < 4; ++r) {
        float mx = sc[0][r];
#pragma unroll
        for (int ct = 1; ct < 8; ++ct) mx = fmaxf(mx, sc[ct][r]);
        mx = row16_max(mx);
        float l = 0.f;
#pragma unroll
        for (int ct = 0; ct < 8; ++ct) {
            float pv = expf(sc[ct][r] - mx);
            sc[ct][r] = pv;
            l += pv;
        }
        l = row16_sum(l);
        rl[r] = 1.f / l;
    }
    // P pre-scaled by 1/l -> LDS, then swapped-operand PV
    ushort_t* Pw = Ps + w * 16 * 128;
#pragma unroll
    for (int ct = 0; ct < 8; ++ct)
#pragma unroll
        for (int r = 0; r < 4; ++r)
            Pw[(quad * 4 + r) * 128 + ct * 16 + l16] = f2b(sc[ct][r] * rl[r]);

    short8 aP[4];
#pragma unroll
    for (int kc = 0; kc < 4; ++kc)
        aP[kc] = *(const short8*)(Pw + l16 * 128 + kc * 32 + quad * 8);

    const int qg = i0 + w * 16 + l16;
    const size_t obase = (size_t)(qg * B_ + b) * QKV_LD + noff;
#pragma unroll
    for (int dt = 0; dt < 4; ++dt) {
        f32x4 accT = {0.f, 0.f, 0.f, 0.f};
#pragma unroll
        for (int kc = 0; kc < 4; ++kc) {
            short8 bV = *(const short8*)(VT + (dt * 16 + l16) * 128 + kc * 32 + quad * 8);
            accT = __builtin_amdgcn_mfma_f32_16x16x32_bf16(bV, aP[kc], accT, 0, 0, 0);
        }
        // accT[r]: O[q = l16][d = dt*16 + quad*4 + r] -> 8B packed store
        uint2 pk;
        pk.x = (unsigned)f2b(accT[0]) | ((unsigned)f2b(accT[1]) << 16);
        pk.y = (unsigned)f2b(accT[2]) | ((unsigned)f2b(accT[3]) << 16);
        *(uint2*)(qkv + obase + dt * 16 + quad * 4) = pk;
    }
}

// h = LayerNorm(x + h)*w + b. Wave-per-row, uint4, no barriers.
__global__ __launch_bounds__(256) void add_ln_kernel(
    const ushort_t* __restrict__ x, ushort_t* __restrict__ h,
    const void* __restrict__ w, const void* __restrict__ b, size_t boff,
    const unsigned int* __restrict__ dtp) {
    const bool isbf = (dtp[0] != FP32_ONE);
    int lane = threadIdx.x & 63;
    int row = blockIdx.x * 4 + (threadIdx.x >> 6);
    size_t base = (size_t)row * D_ + lane * 8;
    ushort_t xe[8], he[8];
    *(uint4*)xe = *(const uint4*)(x + base);
    *(uint4*)he = *(const uint4*)(h + base);
    float v[8];
    float s = 0.f, ss = 0.f;
#pragma unroll
    for (int e = 0; e < 8; ++e) {
        v[e] = b2f(xe[e]) + b2f(he[e]);
        s += v[e]; ss += v[e] * v[e];
    }
    dpp_sum64(s); dpp_sum64(ss);
    float S = rlane(s, 63), SS = rlane(ss, 63);
    float mu  = S * (1.f / D_);
    float var = fmaxf(SS * (1.f / D_) - mu * mu, 0.f);
    float inv = rsqrtf(var + 1e-8f);
    ushort_t oe[8];
#pragma unroll
    for (int e = 0; e < 8; ++e)
        oe[e] = f2b((v[e] - mu) * inv * ldx(w, boff + lane * 8 + e, isbf)
                    + ldx(b, boff + lane * 8 + e, isbf));
    *(uint4*)(h + base) = *(uint4*)oe;
}

__global__ __launch_bounds__(256) void writeout_kernel(const ushort_t* __restrict__ h,
                                                       void* __restrict__ out,
                                                       const unsigned int* __restrict__ dtp) {
    const bool isbf = (dtp[0] != FP32_ONE);
    int idx = blockIdx.x * 256 + threadIdx.x;        // over M_*D_/8
    int d8 = idx & 63;
    int rest = idx >> 6;                             // b*S + s
    int s = rest & (S_ - 1), b = rest >> 9;
    ushort_t ve[8];
    *(uint4*)ve = *(const uint4*)(h + ((size_t)(s * B_ + b) << 9) + d8 * 8);
    if (isbf) {
        *(uint4*)((ushort_t*)out + (size_t)idx * 8) = *(uint4*)ve;
    } else {
        float* op = (float*)out + (size_t)idx * 8;
        ((float4*)op)[0] = make_float4(b2f(ve[0]), b2f(ve[1]), b2f(ve[2]), b2f(ve[3]));
        ((float4*)op)[1] = make_float4(b2f(ve[4]), b2f(ve[5]), b2f(ve[6]), b2f(ve[7]));
    }
}

extern "C" void kernel_launch(void* const* d_in, const int* in_sizes, int n_in,
                              void* d_out, int out_size, void* d_ws, size_t ws_size,
                              hipStream_t stream) {
    (void)in_sizes; (void)n_in; (void)out_size; (void)ws_size;
    const int*  ids = (const int*)d_in[0];
    const void* im  = d_in[1];
    const void* emb = d_in[2];
    const void* Wq = d_in[3], *Wk = d_in[4], *Wv = d_in[5], *Wr = d_in[6], *Wo = d_in[7];
    const void* rrb = d_in[8], *rwb = d_in[9];
    const void* lnaw = d_in[10], *lnab = d_in[11];
    const void* W1 = d_in[12], *b1 = d_in[13], *W2 = d_in[14], *b2 = d_in[15];
    const void* lnfw = d_in[16], *lnfb = d_in[17];
    const unsigned int* dtp = (const unsigned int*)d_in[10];  // dtype probe

    // ---- workspace layout, ~160 MB (ws ≈ 400 MB per r8 poison-fill counters) ----
    char* wsb = (char*)d_ws;
    ushort_t* h    = (ushort_t*)wsb;                   // [0,16)    bf16 16384x512
    ushort_t* qkv  = (ushort_t*)(wsb + (16u << 20));   // [16,64)   bf16 16384x1536
    ushort_t* tmp  = (ushort_t*)(wsb + (64u << 20));   // [64,80)   bf16 16384x512
    ushort_t* ff1  = (ushort_t*)(wsb + (80u << 20));   // [80,144)  bf16 16384x2048
    ushort_t* wbuf = (ushort_t*)(wsb + (144u << 20));  // [144,157) weights
    ushort_t* posb = (ushort_t*)(wsb + (157u << 20));  // [157,158) bf16 1024x512
    ushort_t* krb0 = (ushort_t*)(wsb + (158u << 20));  // [158,159) bf16 1024x512
    ushort_t* krb1 = (ushort_t*)(wsb + (159u << 20));  // [159,160)

    embed_kernel<<<4096, 256, 0, stream>>>(ids, emb, h, dtp);
    posemb_kernel<<<1024, 256, 0, stream>>>(posb);

    transp_cvt4<<<dim3(16, 16, 8), 256, 0, stream>>>(Wq, Wk, Wv, Wr, wbuf, dtp);
    cvtL<<<dim3(1024, 1, 2), 256, 0, stream>>>(Wo, 262144, wbuf, 1048576, dtp, 262144);
    transp_cvtL<<<dim3(64, 16, 2), 256, 0, stream>>>(W1, 1048576, wbuf, 1310720, dtp, 512, 2048);
    transp_cvtL<<<dim3(16, 64, 2), 256, 0, stream>>>(W2, 1048576, wbuf, 2359296, dtp, 2048, 512);

    // k_r for both layers upfront
    mfma_gemm<0><<<dim3(8, 4), 256, 0, stream>>>(posb, 512, wbuf + 786432, 512, nullptr, 0, krb0, 512, dtp, 1024, 512, 512);
    mfma_gemm<0><<<dim3(8, 4), 256, 0, stream>>>(posb, 512, wbuf + WL + 786432, 512, nullptr, 0, krb1, 512, dtp, 1024, 512, 512);

    for (int l = 0; l < 2; ++l) {
        size_t boff = (size_t)l * 512;
        size_t b1off = (size_t)l * 2048;
        ushort_t* qkvT = wbuf + (size_t)l * WL;
        ushort_t* woc  = qkvT + 1048576;
        ushort_t* w1T  = woc  + 262144;
        ushort_t* w2T  = w1T  + 1048576;
        ushort_t* krb  = l ? krb1 : krb0;

        // fused q|k|v = h @ [Wq|Wk|Wv] (16384x1536)
        mfma_gemm<0><<<dim3(128, 12), 256, 0, stream>>>(h, 512, qkvT, 512, nullptr, 0, qkv, QKV_LD, dtp, M_, QKV_LD, 512);

        attn_mfma<<<dim3(8, 32, 8), 256, 0, stream>>>(qkv, krb, rwb, rrb, boff, im, dtp);

        // attn_out = av @ Wo^T (av in q slots, lda=1536)
        mfma_gemm<0><<<dim3(128, 4), 256, 0, stream>>>(qkv, QKV_LD, woc, 512, nullptr, 0, tmp, 512, dtp, M_, 512, 512);
        add_ln_kernel<<<4096, 256, 0, stream>>>(tmp, h, lnaw, lnab, boff, dtp);

        // FFN: single FF1 (N=2048) and single FF2 (K=2048)
        mfma_gemm<2><<<dim3(128, 16), 256, 0, stream>>>(h, 512, w1T, 512, b1, b1off, ff1, DI, dtp, M_, DI, 512);
        mfma_gemm<1><<<dim3(128, 4),  256, 0, stream>>>(ff1, DI, w2T, 2048, b2, boff, tmp, 512, dtp, M_, 512, DI);
        add_ln_kernel<<<4096, 256, 0, stream>>>(tmp, h, lnfw, lnfb, boff, dtp);
    }

    writeout_kernel<<<4096, 256, 0, stream>>>(h, d_out, dtp);
}